// Round 2
// baseline (445.560 us; speedup 1.0000x reference)
//
#include <hip/hip_runtime.h>
#include <math.h>
#include <stdint.h>

#define ALPHA 0.1f
#define EPS 1e-7f

constexpr int D = 65;                  // 1 time-like + 64 space dims
constexpr int A = 16;                  // anchors
constexpr int RPW = 64;                // rows per tile (one wave, one thread/row)
constexpr int TILE_FLOATS = RPW * D;   // 4160 floats = 16640 B
constexpr int NBLOCKS = 1024;          // 4 blocks/CU x 256 CU; LDS caps residency at 4/CU

// ---------------------------------------------------------------------------
// async global->LDS DMA helpers (gfx950: size 4 or 16). LDS dest is
// wave-uniform base + lane*size; global addr is per-lane.
// ---------------------------------------------------------------------------
__device__ __forceinline__ void async_cp16(const float* g, float* l) {
    __builtin_amdgcn_global_load_lds(
        (const __attribute__((address_space(1))) uint32_t*)(uintptr_t)g,
        (__attribute__((address_space(3))) uint32_t*)(uint32_t)(uintptr_t)l,
        16, 0, 0);
}
__device__ __forceinline__ void async_cp4(const float* g, float* l) {
    __builtin_amdgcn_global_load_lds(
        (const __attribute__((address_space(1))) uint32_t*)(uintptr_t)g,
        (__attribute__((address_space(3))) uint32_t*)(uint32_t)(uintptr_t)l,
        4, 0, 0);
}

// ---------------------------------------------------------------------------
// Prep: project anchors, write to ws:
//   ws[0 .. A*D)      : transposed  aT[j*A + a]  (wave-uniform s_loads)
//   ws[A*D .. 2*A*D)  : row-major   aRM[a*D + j] (staged to LDS for na)
// ---------------------------------------------------------------------------
__global__ void prep_anchors(const float* __restrict__ anchors,
                             float* __restrict__ ws) {
    __shared__ float s_a[A * D];
    int tid = threadIdx.x;
    for (int i = tid; i < A * D; i += blockDim.x) s_a[i] = anchors[i];
    __syncthreads();
    if (tid < A) {
        float s = 0.f;
        for (int j = 1; j < D; ++j) {
            float v = s_a[tid * D + j];
            s = fmaf(v, v, s);
        }
        s_a[tid * D] = sqrtf(1.f + s);
    }
    __syncthreads();
    for (int i = tid; i < A * D; i += blockDim.x) {
        int a = i / D, j = i % D;
        ws[j * A + a] = s_a[i];    // transposed
        ws[A * D + i] = s_a[i];    // row-major (projected)
    }
}

// ---------------------------------------------------------------------------
// Per-row math: 16 Lorentz inner products (aT via wave-uniform s_loads),
// argmin, exp-map update. out_j = (ch + sc*xy)*x_j + sc*na_j (algebraically
// identical to ch*x + sc*(na + xy*x), saves 65 FMAs/row).
// ---------------------------------------------------------------------------
__device__ __forceinline__ void row_math(const float xr[D],
                                         const float* __restrict__ aT,
                                         const float* __restrict__ anch,
                                         float* __restrict__ orow) {
    float acc[A];
#pragma unroll
    for (int a = 0; a < A; ++a) acc[a] = -xr[0] * aT[a];
#pragma unroll
    for (int j = 1; j < D; ++j) {
        const float xj = xr[j];
#pragma unroll
        for (int a = 0; a < A; ++a)
            acc[a] = fmaf(xj, aT[j * A + a], acc[a]);
    }

    // argmin of acosh(max(-inner,1+eps)); strict < = first-index ties
    const float onePlusEps = 1.0f + EPS;
    float bestZ = fmaxf(-acc[0], onePlusEps);
    float xy = acc[0];
    int bidx = 0;
#pragma unroll
    for (int a = 1; a < A; ++a) {
        float z = fmaxf(-acc[a], onePlusEps);
        if (z < bestZ) { bestZ = z; bidx = a; xy = acc[a]; }
    }
    const float d = acoshf(bestZ);

    // na reads: same-bidx lanes broadcast, distinct-bidx lanes hit distinct
    // banks ((bidx+j)%32, bidx<16) -> conflict-free
    const float* na = anch + bidx * D;
    float uu;
    {
        float u0 = fmaf(xy, xr[0], na[0]);
        uu = -u0 * u0;
    }
#pragma unroll
    for (int j = 1; j < D; ++j) {
        float uj = fmaf(xy, xr[j], na[j]);
        uu = fmaf(uj, uj, uu);
    }
    const float unorm = sqrtf(fmaxf(uu, EPS));
    const float c = ALPHA * d / unorm;
    const float vv = c * c * uu;
    const float vn = sqrtf(fmaxf(vv, EPS * EPS));
    const float sinhc = (vn > EPS) ? (sinhf(vn) / vn) : 1.0f;
    const float ch = coshf(vn);
    const float sc = sinhc * c;
    const float k1 = fmaf(sc, xy, ch);    // ch + sc*xy
#pragma unroll
    for (int j = 0; j < D; ++j)
        orow[j] = fmaf(k1, xr[j], sc * na[j]);
}

// ---------------------------------------------------------------------------
// Main: persistent single-wave blocks, grid-stride over 64-row tiles with a
// one-tile-ahead LDS double buffer. No barriers in the loop; all ordering is
// wave-local waitcnt.
//
// vmcnt contract: per full tile we issue exactly 17 DMA ops (16x cp16 + 1x
// cp4) and exactly 17 store ops (16x dwordx4 + 1x dword). At the top of each
// iteration we first issue the 17-op prefetch for tile t+stride, then
// `s_waitcnt vmcnt(17)`: vmcnt retires in issue order, so allowing the 17
// youngest ops to stay outstanding (= the just-issued prefetch, or the 17
// stores of the previous tile on the last iteration) guarantees DMA(t) and
// all older stores have retired. Compiler-inserted vmem between the groups
// only makes the wait more conservative, never incorrect. No scratch spills
// (~110 VGPR under __launch_bounds__(64,1)) to inflate the count.
// ---------------------------------------------------------------------------
__global__ __launch_bounds__(64, 1) void
homeo_kernel(const float* __restrict__ x,
             const float* __restrict__ aT,    // [D][A] transposed, projected
             const float* __restrict__ aRM,   // [A][D] row-major, projected
             float* __restrict__ out, int B) {
    __shared__ float buf[2][TILE_FLOATS];     // 2 x 16640 B
    __shared__ float anch[A * D];             // 4160 B -> 37440 B/block -> 4 blocks/CU

    const int lane = threadIdx.x;             // 0..63, one wave per block
    const long stride = gridDim.x;
    const int nTiles = (B + RPW - 1) / RPW;

    // anchors -> LDS (once per block; hot in L2/L3, ~0 HBM)
    for (int i = lane; i < A * D; i += 64) anch[i] = aRM[i];

    // prologue: DMA first tile into buf[0]
    {
        const long t0 = blockIdx.x;
        if (t0 < nTiles && (t0 + 1) * (long)RPW <= (long)B) {
            const float* g = x + t0 * (long)TILE_FLOATS;
#pragma unroll
            for (int c = 0; c < 16; ++c)
                async_cp16(g + c * 256 + lane * 4, buf[0] + c * 256);
            async_cp4(g + 16 * 256 + lane, buf[0] + 16 * 256);
        }
    }
    __syncthreads();   // anchors visible; drains prologue DMA (once)

    int p = 0;
    for (long t = blockIdx.x; t < nTiles; t += stride, p ^= 1) {
        const long rowStart = t * RPW;
        const int nRows = (int)min((long)RPW, (long)B - rowStart);

        // ---- prefetch next tile into the other buffer (issued BEFORE the
        // wait: its 17 ops are the allowed-outstanding budget below) ----
        {
            const long tn = t + stride;
            if (tn < nTiles && (tn + 1) * (long)RPW <= (long)B) {
                const float* g = x + tn * (long)TILE_FLOATS;
                float* l = buf[p ^ 1];
#pragma unroll
                for (int c = 0; c < 16; ++c)
                    async_cp16(g + c * 256 + lane * 4, l + c * 256);
                async_cp4(g + 16 * 256 + lane, l + 16 * 256);
            }
        }
        // everything except the 17 youngest vmem ops has retired:
        // DMA(t) complete, previous tile's stores complete.
        asm volatile("s_waitcnt vmcnt(17)" ::: "memory");

        float* lbase = buf[p];
        if (nRows == RPW) {
            // row into registers: bank = (lane + j) % 32 -> 2-way, free
            float xr[D];
#pragma unroll
            for (int j = 0; j < D; ++j) xr[j] = lbase[lane * D + j];

            // compute; result written back into this tile's LDS (transposed
            // store staging)
            row_math(xr, aT, anch, lbase + lane * D);

            // wave-local fence: all lanes' LDS writes retired before
            // cross-lane reads in the coalesced store below
            asm volatile("s_waitcnt lgkmcnt(0)" ::: "memory");

            // exactly 17 stores — part of the vmcnt(17) contract above
            float4* o4 = (float4*)(out + rowStart * (long)D);
            const float4* l4 = (const float4*)lbase;
#pragma unroll
            for (int c2 = 0; c2 < 16; ++c2)
                o4[c2 * 64 + lane] = l4[c2 * 64 + lane];
            out[rowStart * (long)D + 16 * 256 + lane] = lbase[16 * 256 + lane];
        } else if (lane < nRows) {
            // partial tile (unused at B=1e6: 15625 full tiles exactly).
            // No DMA was issued for it; read/write global directly.
            const float* xg = x + (rowStart + lane) * (long)D;
            float xr[D];
            for (int j = 0; j < D; ++j) xr[j] = xg[j];
            row_math(xr, aT, anch, out + (rowStart + lane) * (long)D);
        }
    }
}

extern "C" void kernel_launch(void* const* d_in, const int* in_sizes, int n_in,
                              void* d_out, int out_size, void* d_ws, size_t ws_size,
                              hipStream_t stream) {
    const float* hyp = (const float*)d_in[0];
    const float* anchors = (const float*)d_in[1];
    float* out = (float*)d_out;
    float* ws = (float*)d_ws;

    const int B = in_sizes[0] / D;                 // 1,000,000
    const int nTiles = (B + RPW - 1) / RPW;        // 15,625 tiles
    const int grid = nTiles < NBLOCKS ? nTiles : NBLOCKS;

    prep_anchors<<<1, 256, 0, stream>>>(anchors, ws);
    homeo_kernel<<<grid, 64, 0, stream>>>(hyp, ws, ws + A * D, out, B);
}